// Round 1
// baseline (5249.870 us; speedup 1.0000x reference)
//
#include <hip/hip_runtime.h>
#include <hip/hip_bf16.h>

// RGCN 2-layer, fp32 baseline.
// Layer: agg[dst] += (x @ W[etype])[src] / count(dst,etype);  out = agg + x@root + b
// Strategy: per-relation GEMM into a reused H buffer, then atomic scatter.

#define N_REL 8
#define TILE 64
#define BK 16

__global__ __launch_bounds__(256) void count_kernel(const int* __restrict__ dst,
                                                    const int* __restrict__ et,
                                                    int* __restrict__ cnt, int E) {
    int e = blockIdx.x * blockDim.x + threadIdx.x;
    if (e < E) atomicAdd(&cnt[dst[e] * N_REL + et[e]], 1);
}

// C[M,N] = A[M,K] @ B[K,N] (+ bias[N] if bias != null). Row-major. N % 64 == 0, K % 16 == 0.
__global__ __launch_bounds__(256) void gemm64(const float* __restrict__ A,
                                              const float* __restrict__ B,
                                              const float* __restrict__ bias,
                                              float* __restrict__ C,
                                              int M, int K, int N) {
    __shared__ float As[BK][TILE + 4];  // As[k][m], +4 pad keeps float4 alignment
    __shared__ float Bs[BK][TILE + 4];  // Bs[k][n]

    const int bm = blockIdx.x * TILE;
    const int bn = blockIdx.y * TILE;
    const int t  = threadIdx.x;
    const int tx = t & 15;        // -> n micro-tile
    const int ty = t >> 4;        // -> m micro-tile

    // A-load mapping: thread loads float4 at row am, cols ak..ak+3
    const int am = t >> 2;             // 0..63
    const int ak = (t & 3) * 4;        // 0,4,8,12
    // B-load mapping: thread loads float4 at row bk, cols bnn..bnn+3
    const int bk  = t >> 4;            // 0..15
    const int bnn = (t & 15) * 4;      // 0..60

    float acc[4][4];
#pragma unroll
    for (int i = 0; i < 4; ++i)
#pragma unroll
        for (int j = 0; j < 4; ++j) acc[i][j] = 0.f;

    for (int k0 = 0; k0 < K; k0 += BK) {
        // load A tile (64 x 16), transposed into As[k][m]
        float4 a4 = {0.f, 0.f, 0.f, 0.f};
        int gm = bm + am;
        if (gm < M) a4 = *(const float4*)(A + (size_t)gm * K + k0 + ak);
        As[ak + 0][am] = a4.x;
        As[ak + 1][am] = a4.y;
        As[ak + 2][am] = a4.z;
        As[ak + 3][am] = a4.w;
        // load B tile (16 x 64)
        float4 b4 = *(const float4*)(B + (size_t)(k0 + bk) * N + bn + bnn);
        *(float4*)&Bs[bk][bnn] = b4;
        __syncthreads();

#pragma unroll
        for (int k = 0; k < BK; ++k) {
            float4 av = *(float4*)&As[k][ty * 4];
            float4 bv = *(float4*)&Bs[k][tx * 4];
            float a_[4] = {av.x, av.y, av.z, av.w};
            float b_[4] = {bv.x, bv.y, bv.z, bv.w};
#pragma unroll
            for (int i = 0; i < 4; ++i)
#pragma unroll
                for (int j = 0; j < 4; ++j) acc[i][j] += a_[i] * b_[j];
        }
        __syncthreads();
    }

    const int gn = bn + tx * 4;
    float4 bv = {0.f, 0.f, 0.f, 0.f};
    if (bias) bv = *(const float4*)(bias + gn);
#pragma unroll
    for (int i = 0; i < 4; ++i) {
        int gm = bm + ty * 4 + i;
        if (gm < M) {
            float4 o;
            o.x = acc[i][0] + bv.x;
            o.y = acc[i][1] + bv.y;
            o.z = acc[i][2] + bv.z;
            o.w = acc[i][3] + bv.w;
            *(float4*)(C + (size_t)gm * N + gn) = o;
        }
    }
}

// For each edge of relation `rel`: agg[dst] += H[src] / count(dst,rel)
__global__ __launch_bounds__(256) void scatter_kernel(const float* __restrict__ H,
                                                      const int* __restrict__ cnt,
                                                      const int* __restrict__ src,
                                                      const int* __restrict__ dst,
                                                      const int* __restrict__ et,
                                                      float* __restrict__ agg,
                                                      int E, int dim, int rel) {
    int e = blockIdx.x;
    int r = et[e];
    if (r != rel) return;
    int s = src[e], d = dst[e];
    int c = cnt[d * N_REL + r];
    float inv = 1.0f / (float)(c > 0 ? c : 1);
    const float* hrow = H + (size_t)s * dim;
    float* arow = agg + (size_t)d * dim;
    for (int i = threadIdx.x; i < dim; i += blockDim.x)
        atomicAdd(&arow[i], hrow[i] * inv);
}

__global__ __launch_bounds__(256) void relu_kernel(float* __restrict__ x, int n) {
    int i = blockIdx.x * blockDim.x + threadIdx.x;
    if (i < n) x[i] = fmaxf(x[i], 0.f);
}

extern "C" void kernel_launch(void* const* d_in, const int* in_sizes, int n_in,
                              void* d_out, int out_size, void* d_ws, size_t ws_size,
                              hipStream_t stream) {
    const float* x     = (const float*)d_in[0];
    const int*   eidx  = (const int*)d_in[1];
    const int*   etype = (const int*)d_in[2];
    const float* W1    = (const float*)d_in[3];
    const float* root1 = (const float*)d_in[4];
    const float* b1    = (const float*)d_in[5];
    const float* W2    = (const float*)d_in[6];
    const float* root2 = (const float*)d_in[7];
    const float* b2    = (const float*)d_in[8];
    float* out = (float*)d_out;

    const int IN_DIM = 1280, HID_DIM = 512, OUT_DIM = 256;
    const int E = in_sizes[2];
    const int N = in_sizes[0] / IN_DIM;
    const int* srcs = eidx;
    const int* dsts = eidx + E;

    // workspace layout
    char* ws = (char*)d_ws;
    int*   cnt  = (int*)ws;                                        // N*8 ints (640 KB)
    float* Hbuf = (float*)(ws + (1 << 20));                        // N*512 floats (41 MB)
    float* hbuf = (float*)(ws + (1 << 20) + (size_t)N * HID_DIM * 4); // N*512 floats (41 MB)

    // 1) per-(dst, rel) edge counts
    hipMemsetAsync(cnt, 0, (size_t)N * N_REL * sizeof(int), stream);
    count_kernel<<<(E + 255) / 256, 256, 0, stream>>>(dsts, etype, cnt, E);

    const int mblk = (N + TILE - 1) / TILE;

    // 2) layer 1: hbuf = x @ root1 + b1, then += mean-scatter of x @ W1[r]
    gemm64<<<dim3(mblk, HID_DIM / TILE), 256, 0, stream>>>(x, root1, b1, hbuf, N, IN_DIM, HID_DIM);
    for (int r = 0; r < N_REL; ++r) {
        gemm64<<<dim3(mblk, HID_DIM / TILE), 256, 0, stream>>>(
            x, W1 + (size_t)r * IN_DIM * HID_DIM, nullptr, Hbuf, N, IN_DIM, HID_DIM);
        scatter_kernel<<<E, 256, 0, stream>>>(Hbuf, cnt, srcs, dsts, etype, hbuf, E, HID_DIM, r);
    }
    relu_kernel<<<((size_t)N * HID_DIM + 255) / 256, 256, 0, stream>>>(hbuf, N * HID_DIM);

    // 3) layer 2: out = hbuf @ root2 + b2, then += mean-scatter of hbuf @ W2[r]
    gemm64<<<dim3(mblk, OUT_DIM / TILE), 256, 0, stream>>>(hbuf, root2, b2, out, N, HID_DIM, OUT_DIM);
    for (int r = 0; r < N_REL; ++r) {
        gemm64<<<dim3(mblk, OUT_DIM / TILE), 256, 0, stream>>>(
            hbuf, W2 + (size_t)r * HID_DIM * OUT_DIM, nullptr, Hbuf, N, HID_DIM, OUT_DIM);
        scatter_kernel<<<E, 256, 0, stream>>>(Hbuf, cnt, srcs, dsts, etype, out, E, OUT_DIM, r);
    }
}

// Round 2
// 4325.570 us; speedup vs baseline: 1.2137x; 1.2137x over previous
//
#include <hip/hip_runtime.h>
#include <hip/hip_bf16.h>

#define N_REL 8
#define TM 128
#define TN 128
#define BK 32

typedef unsigned short ushort_t;
typedef __attribute__((ext_vector_type(8))) short short8;   // bf16x8 MFMA operand (4 VGPRs)
typedef __attribute__((ext_vector_type(4))) float floatx4;  // MFMA accumulator

static __device__ __forceinline__ ushort_t f2bf(float f) {
    union { float f; unsigned u; } v; v.f = f;
    unsigned r = v.u + 0x7fff + ((v.u >> 16) & 1);  // round-to-nearest-even
    return (ushort_t)(r >> 16);
}

typedef __attribute__((address_space(1))) void glob_void;
typedef __attribute__((address_space(3))) void lds_void;

static __device__ __forceinline__ void load_lds16(const void* g, void* l) {
    __builtin_amdgcn_global_load_lds((glob_void*)g, (lds_void*)l, 16, 0, 0);
}

// ---------------- prep kernels ----------------

__global__ __launch_bounds__(256) void count_kernel(const int* __restrict__ dst,
                                                    const int* __restrict__ et,
                                                    int* __restrict__ cnt, int E) {
    int e = blockIdx.x * blockDim.x + threadIdx.x;
    if (e < E) atomicAdd(&cnt[dst[e] * N_REL + et[e]], 1);
}

__global__ __launch_bounds__(256) void cast_bf16(const float* __restrict__ in,
                                                 ushort_t* __restrict__ out, long n) {
    long idx = ((long)blockIdx.x * blockDim.x + threadIdx.x) * 4;
    if (idx + 4 <= n) {
        float4 v = *(const float4*)(in + idx);
        ushort_t o[4] = {f2bf(v.x), f2bf(v.y), f2bf(v.z), f2bf(v.w)};
        *(uint2*)(out + idx) = *(const uint2*)o;
    } else {
        for (; idx < n; ++idx) out[idx] = f2bf(in[idx]);
    }
}

__global__ __launch_bounds__(256) void relu_cast_bf16(const float* __restrict__ in,
                                                      ushort_t* __restrict__ out, long n) {
    long idx = ((long)blockIdx.x * blockDim.x + threadIdx.x) * 4;
    if (idx + 4 <= n) {
        float4 v = *(const float4*)(in + idx);
        ushort_t o[4] = {f2bf(fmaxf(v.x, 0.f)), f2bf(fmaxf(v.y, 0.f)),
                         f2bf(fmaxf(v.z, 0.f)), f2bf(fmaxf(v.w, 0.f))};
        *(uint2*)(out + idx) = *(const uint2*)o;
    } else {
        for (; idx < n; ++idx) out[idx] = f2bf(fmaxf(in[idx], 0.f));
    }
}

// in: [z][K][N] fp32 -> out: [z][N][K] bf16.  K, N multiples of 32. block = 256 (32x8).
__global__ __launch_bounds__(256) void transpose_cast(const float* __restrict__ in,
                                                      ushort_t* __restrict__ out,
                                                      int K, int N) {
    __shared__ float tile[32][33];
    const float* inp = in + (size_t)blockIdx.z * K * N;
    ushort_t* outp = out + (size_t)blockIdx.z * K * N;
    int n0 = blockIdx.x * 32, k0 = blockIdx.y * 32;
    int tx = threadIdx.x & 31, ty = threadIdx.x >> 5;
#pragma unroll
    for (int s = 0; s < 4; ++s)
        tile[ty + 8 * s][tx] = inp[(size_t)(k0 + ty + 8 * s) * N + n0 + tx];
    __syncthreads();
#pragma unroll
    for (int s = 0; s < 4; ++s)
        outp[(size_t)(n0 + ty + 8 * s) * K + k0 + tx] = f2bf(tile[tx][ty + 8 * s]);
}

// ---------------- MFMA GEMM: C[M,N] = A[M,K] @ Bt[N,K]^T (+bias) ----------------
// A, Bt bf16 row-major (K-contiguous). C fp32. K%32==0, N%128==0. M guarded.
__global__ __launch_bounds__(256) void gemm_bt_bf16(const ushort_t* __restrict__ A,
                                                    const ushort_t* __restrict__ Bt,
                                                    const float* __restrict__ bias,
                                                    float* __restrict__ C,
                                                    int M, int K, int N) {
    __shared__ __align__(16) ushort_t As[TM * BK];
    __shared__ __align__(16) ushort_t Bs[TN * BK];

    const int t = threadIdx.x;
    const int lane = t & 63;
    const int wave = t >> 6;               // 0..3
    const int wm = wave >> 1, wn = wave & 1;
    const int quad = lane >> 4, l16 = lane & 15;

    const int bm = blockIdx.x * TM;
    const int bn = blockIdx.y * TN;

    // staging mapping: chunk = 16 rows x 32 k (1024 B); lane -> row lane>>2, k-grp (lane&3)*8
    const int ar = lane >> 2;
    const int ac = (lane & 3) * 8;

    floatx4 acc[4][4];
#pragma unroll
    for (int i = 0; i < 4; ++i)
#pragma unroll
        for (int j = 0; j < 4; ++j) acc[i][j] = (floatx4)(0.f);

    for (int k0 = 0; k0 < K; k0 += BK) {
#pragma unroll
        for (int cc = 0; cc < 2; ++cc) {
            const int c = 2 * wave + cc;
            int gra = bm + c * 16 + ar;
            gra = gra < M ? gra : M - 1;                 // clamp OOB rows (stores guarded)
            load_lds16(A + (size_t)gra * K + k0 + ac, As + c * 16 * BK);
            int grb = bn + c * 16 + ar;
            load_lds16(Bt + (size_t)grb * K + k0 + ac, Bs + c * 16 * BK);
        }
        __syncthreads();

        short8 af[4], bfr[4];
#pragma unroll
        for (int i = 0; i < 4; ++i)
            af[i] = *(const short8*)&As[(wm * 64 + i * 16 + l16) * BK + quad * 8];
#pragma unroll
        for (int j = 0; j < 4; ++j)
            bfr[j] = *(const short8*)&Bs[(wn * 64 + j * 16 + l16) * BK + quad * 8];
#pragma unroll
        for (int i = 0; i < 4; ++i)
#pragma unroll
            for (int j = 0; j < 4; ++j)
                acc[i][j] = __builtin_amdgcn_mfma_f32_16x16x32_bf16(af[i], bfr[j], acc[i][j], 0, 0, 0);
        __syncthreads();
    }

    // epilogue: C/D layout col=lane&15, row=quad*4+reg
#pragma unroll
    for (int j = 0; j < 4; ++j) {
        int col = bn + wn * 64 + j * 16 + l16;
        float bv = bias ? bias[col] : 0.f;
#pragma unroll
        for (int i = 0; i < 4; ++i) {
            int row0 = bm + wm * 64 + i * 16 + quad * 4;
#pragma unroll
            for (int rg = 0; rg < 4; ++rg) {
                int row = row0 + rg;
                if (row < M) C[(size_t)row * N + col] = acc[i][j][rg] + bv;
            }
        }
    }
}

// ---------------- scatter: agg[dst] += H[src]/cnt(dst,rel) for edges of `rel` ----------------
// grid-stride, one 64-lane wave per edge, float4 H reads. dim % 256 == 0.
__global__ __launch_bounds__(256) void scatter_kernel(const float* __restrict__ H,
                                                      const int* __restrict__ cnt,
                                                      const int* __restrict__ src,
                                                      const int* __restrict__ dst,
                                                      const int* __restrict__ et,
                                                      float* __restrict__ agg,
                                                      int E, int dim, int rel) {
    const int lane = threadIdx.x & 63;
    const int wid = blockIdx.x * (blockDim.x >> 6) + (threadIdx.x >> 6);
    const int nw = gridDim.x * (blockDim.x >> 6);
    for (int e = wid; e < E; e += nw) {
        if (et[e] != rel) continue;
        int s = src[e], d = dst[e];
        int c = cnt[d * N_REL + rel];
        float inv = 1.0f / (float)(c > 0 ? c : 1);
        const float* hrow = H + (size_t)s * dim;
        float* arow = agg + (size_t)d * dim;
        for (int o = lane * 4; o < dim; o += 256) {
            float4 v = *(const float4*)(hrow + o);
            atomicAdd(arow + o + 0, v.x * inv);
            atomicAdd(arow + o + 1, v.y * inv);
            atomicAdd(arow + o + 2, v.z * inv);
            atomicAdd(arow + o + 3, v.w * inv);
        }
    }
}

// ---------------- launcher ----------------

extern "C" void kernel_launch(void* const* d_in, const int* in_sizes, int n_in,
                              void* d_out, int out_size, void* d_ws, size_t ws_size,
                              hipStream_t stream) {
    const float* x     = (const float*)d_in[0];
    const int*   eidx  = (const int*)d_in[1];
    const int*   etype = (const int*)d_in[2];
    const float* W1    = (const float*)d_in[3];
    const float* root1 = (const float*)d_in[4];
    const float* b1    = (const float*)d_in[5];
    const float* W2    = (const float*)d_in[6];
    const float* root2 = (const float*)d_in[7];
    const float* b2    = (const float*)d_in[8];
    float* out = (float*)d_out;

    const int IN_DIM = 1280, HID_DIM = 512, OUT_DIM = 256;
    const int E = in_sizes[2];
    const int N = in_sizes[0] / IN_DIM;
    const int* srcs = eidx;
    const int* dsts = eidx + E;

    // workspace layout (256 B aligned)
    char* ws = (char*)d_ws;
    size_t off = 0;
    auto alloc = [&](size_t bytes) { void* p = ws + off; off += (bytes + 255) & ~(size_t)255; return p; };
    int*      cnt   = (int*)alloc((size_t)N * N_REL * sizeof(int));
    ushort_t* x_bf  = (ushort_t*)alloc((size_t)N * IN_DIM * 2);
    ushort_t* W1t   = (ushort_t*)alloc((size_t)N_REL * IN_DIM * HID_DIM * 2);
    ushort_t* r1t   = (ushort_t*)alloc((size_t)IN_DIM * HID_DIM * 2);
    ushort_t* W2t   = (ushort_t*)alloc((size_t)N_REL * HID_DIM * OUT_DIM * 2);
    ushort_t* r2t   = (ushort_t*)alloc((size_t)HID_DIM * OUT_DIM * 2);
    float*    Hbuf  = (float*)alloc((size_t)N * HID_DIM * sizeof(float));
    float*    hbuf  = (float*)alloc((size_t)N * HID_DIM * sizeof(float));
    ushort_t* hb_bf = (ushort_t*)alloc((size_t)N * HID_DIM * 2);
    (void)ws_size;

    // 1) per-(dst,rel) counts
    hipMemsetAsync(cnt, 0, (size_t)N * N_REL * sizeof(int), stream);
    count_kernel<<<(E + 255) / 256, 256, 0, stream>>>(dsts, etype, cnt, E);

    // 2) casts / weight transposes
    {
        long n = (long)N * IN_DIM;
        cast_bf16<<<(unsigned)((n / 4 + 255) / 256), 256, 0, stream>>>(x, x_bf, n);
    }
    transpose_cast<<<dim3(HID_DIM / 32, IN_DIM / 32, N_REL), 256, 0, stream>>>(W1, W1t, IN_DIM, HID_DIM);
    transpose_cast<<<dim3(HID_DIM / 32, IN_DIM / 32, 1), 256, 0, stream>>>(root1, r1t, IN_DIM, HID_DIM);
    transpose_cast<<<dim3(OUT_DIM / 32, HID_DIM / 32, N_REL), 256, 0, stream>>>(W2, W2t, HID_DIM, OUT_DIM);
    transpose_cast<<<dim3(OUT_DIM / 32, HID_DIM / 32, 1), 256, 0, stream>>>(root2, r2t, HID_DIM, OUT_DIM);

    const int mblk = (N + TM - 1) / TM;

    // 3) layer 1
    gemm_bt_bf16<<<dim3(mblk, HID_DIM / TN), 256, 0, stream>>>(x_bf, r1t, b1, hbuf, N, IN_DIM, HID_DIM);
    for (int r = 0; r < N_REL; ++r) {
        gemm_bt_bf16<<<dim3(mblk, HID_DIM / TN), 256, 0, stream>>>(
            x_bf, W1t + (size_t)r * IN_DIM * HID_DIM, nullptr, Hbuf, N, IN_DIM, HID_DIM);
        scatter_kernel<<<2048, 256, 0, stream>>>(Hbuf, cnt, srcs, dsts, etype, hbuf, E, HID_DIM, r);
    }
    {
        long n = (long)N * HID_DIM;
        relu_cast_bf16<<<(unsigned)((n / 4 + 255) / 256), 256, 0, stream>>>(hbuf, hb_bf, n);
    }

    // 4) layer 2
    gemm_bt_bf16<<<dim3(mblk, OUT_DIM / TN), 256, 0, stream>>>(hb_bf, r2t, b2, out, N, HID_DIM, OUT_DIM);
    for (int r = 0; r < N_REL; ++r) {
        gemm_bt_bf16<<<dim3(mblk, OUT_DIM / TN), 256, 0, stream>>>(
            hb_bf, W2t + (size_t)r * HID_DIM * OUT_DIM, nullptr, Hbuf, N, HID_DIM, OUT_DIM);
        scatter_kernel<<<2048, 256, 0, stream>>>(Hbuf, cnt, srcs, dsts, etype, out, E, OUT_DIM, r);
    }
}

// Round 3
// 1777.018 us; speedup vs baseline: 2.9543x; 2.4342x over previous
//
#include <hip/hip_runtime.h>
#include <hip/hip_bf16.h>

#define N_REL 8
#define TM 128
#define TN 128
#define BK 32

typedef unsigned short ushort_t;
typedef unsigned int uint_t;
typedef __attribute__((ext_vector_type(8))) short short8;   // bf16x8 MFMA operand
typedef __attribute__((ext_vector_type(4))) float floatx4;  // MFMA accumulator

static __device__ __forceinline__ ushort_t f2bf(float f) {
    union { float f; unsigned u; } v; v.f = f;
    unsigned r = v.u + 0x7fff + ((v.u >> 16) & 1);
    return (ushort_t)(r >> 16);
}

typedef __attribute__((address_space(1))) void glob_void;
typedef __attribute__((address_space(3))) void lds_void;

static __device__ __forceinline__ void load_lds16(const void* g, void* l) {
    __builtin_amdgcn_global_load_lds((glob_void*)g, (lds_void*)l, 16, 0, 0);
}

// ---------------- sort infrastructure ----------------

__global__ __launch_bounds__(256) void hist_kernel(const int* __restrict__ dst,
                                                   const int* __restrict__ et,
                                                   int* __restrict__ cnt, int E) {
    int e = blockIdx.x * blockDim.x + threadIdx.x;
    if (e < E) atomicAdd(&cnt[dst[e] * N_REL + et[e]], 1);
}

// phase 1: per-256-block exclusive scan, write block sums
__global__ __launch_bounds__(256) void scan1(const int* __restrict__ cnt,
                                             int* __restrict__ off,
                                             int* __restrict__ bsum, int nk) {
    __shared__ int s[256];
    int t = threadIdx.x;
    int k = blockIdx.x * 256 + t;
    int v = k < nk ? cnt[k] : 0;
    s[t] = v; __syncthreads();
    for (int d = 1; d < 256; d <<= 1) {
        int x = (t >= d) ? s[t - d] : 0;
        __syncthreads(); s[t] += x; __syncthreads();
    }
    if (k < nk) off[k] = s[t] - v;          // exclusive
    if (t == 255) bsum[blockIdx.x] = s[255];
}

// phase 2: single block scans block sums (nb <= 1024)
__global__ __launch_bounds__(1024) void scan2(int* __restrict__ bsum, int nb) {
    __shared__ int s[1024];
    int t = threadIdx.x;
    int v = t < nb ? bsum[t] : 0;
    s[t] = v; __syncthreads();
    for (int d = 1; d < 1024; d <<= 1) {
        int x = (t >= d) ? s[t - d] : 0;
        __syncthreads(); s[t] += x; __syncthreads();
    }
    if (t < nb) bsum[t] = s[t] - v;         // exclusive
}

// phase 3: add block offsets, copy to cursor, build per-relation active-dst lists
__global__ __launch_bounds__(256) void scan3(const int* __restrict__ cnt,
                                             int* __restrict__ off,
                                             const int* __restrict__ bsum,
                                             int* __restrict__ cursor,
                                             int* __restrict__ nact,
                                             int* __restrict__ act,
                                             int nk, int n) {
    int k = blockIdx.x * 256 + threadIdx.x;
    if (k >= nk) return;
    int o = off[k] + bsum[k >> 8];
    off[k] = o;
    cursor[k] = o;
    if (cnt[k] > 0) {
        int r = k & 7, d = k >> 3;
        int p = atomicAdd(&nact[r], 1);
        act[r * n + p] = d;
    }
}

__global__ __launch_bounds__(256) void scatter_ids(const int* __restrict__ dst,
                                                   const int* __restrict__ et,
                                                   int* __restrict__ cursor,
                                                   int* __restrict__ eid, int E) {
    int e = blockIdx.x * blockDim.x + threadIdx.x;
    if (e < E) {
        int key = dst[e] * N_REL + et[e];
        int pos = atomicAdd(&cursor[key], 1);
        eid[pos] = e;
    }
}

// ---------------- casts ----------------

__global__ __launch_bounds__(256) void cast_bf16(const float* __restrict__ in,
                                                 ushort_t* __restrict__ out, long n) {
    long idx = ((long)blockIdx.x * blockDim.x + threadIdx.x) * 4;
    if (idx + 4 <= n) {
        float4 v = *(const float4*)(in + idx);
        ushort_t o[4] = {f2bf(v.x), f2bf(v.y), f2bf(v.z), f2bf(v.w)};
        *(uint2*)(out + idx) = *(const uint2*)o;
    } else {
        for (; idx < n; ++idx) out[idx] = f2bf(in[idx]);
    }
}

__global__ __launch_bounds__(256) void relu_cast_bf16(const float* __restrict__ in,
                                                      ushort_t* __restrict__ out, long n) {
    long idx = ((long)blockIdx.x * blockDim.x + threadIdx.x) * 4;
    if (idx + 4 <= n) {
        float4 v = *(const float4*)(in + idx);
        ushort_t o[4] = {f2bf(fmaxf(v.x, 0.f)), f2bf(fmaxf(v.y, 0.f)),
                         f2bf(fmaxf(v.z, 0.f)), f2bf(fmaxf(v.w, 0.f))};
        *(uint2*)(out + idx) = *(const uint2*)o;
    } else {
        for (; idx < n; ++idx) out[idx] = f2bf(fmaxf(in[idx], 0.f));
    }
}

// in: [z][K][N] fp32 -> out: [z][N][K] bf16.
__global__ __launch_bounds__(256) void transpose_cast(const float* __restrict__ in,
                                                      ushort_t* __restrict__ out,
                                                      int K, int N) {
    __shared__ float tile[32][33];
    const float* inp = in + (size_t)blockIdx.z * K * N;
    ushort_t* outp = out + (size_t)blockIdx.z * K * N;
    int n0 = blockIdx.x * 32, k0 = blockIdx.y * 32;
    int tx = threadIdx.x & 31, ty = threadIdx.x >> 5;
#pragma unroll
    for (int s = 0; s < 4; ++s)
        tile[ty + 8 * s][tx] = inp[(size_t)(k0 + ty + 8 * s) * N + n0 + tx];
    __syncthreads();
#pragma unroll
    for (int s = 0; s < 4; ++s)
        outp[(size_t)(n0 + ty + 8 * s) * K + k0 + tx] = f2bf(tile[tx][ty + 8 * s]);
}

// ---------------- MFMA GEMM: C[M,N] = A[M,K] @ Bt[N,K]^T (+bias) ----------------
template <typename OutT>
__global__ __launch_bounds__(256) void gemm_bt(const ushort_t* __restrict__ A,
                                               const ushort_t* __restrict__ Bt,
                                               const float* __restrict__ bias,
                                               OutT* __restrict__ C,
                                               int M, int K, int N) {
    __shared__ __align__(16) ushort_t As[TM * BK];
    __shared__ __align__(16) ushort_t Bs[TN * BK];

    const int t = threadIdx.x;
    const int lane = t & 63;
    const int wave = t >> 6;
    const int wm = wave >> 1, wn = wave & 1;
    const int quad = lane >> 4, l16 = lane & 15;

    const int bm = blockIdx.x * TM;
    const int bn = blockIdx.y * TN;

    const int ar = lane >> 2;
    const int ac = (lane & 3) * 8;

    floatx4 acc[4][4];
#pragma unroll
    for (int i = 0; i < 4; ++i)
#pragma unroll
        for (int j = 0; j < 4; ++j) acc[i][j] = (floatx4)(0.f);

    for (int k0 = 0; k0 < K; k0 += BK) {
#pragma unroll
        for (int cc = 0; cc < 2; ++cc) {
            const int c = 2 * wave + cc;
            int gra = bm + c * 16 + ar;
            gra = gra < M ? gra : M - 1;
            load_lds16(A + (size_t)gra * K + k0 + ac, As + c * 16 * BK);
            int grb = bn + c * 16 + ar;
            load_lds16(Bt + (size_t)grb * K + k0 + ac, Bs + c * 16 * BK);
        }
        __syncthreads();

        short8 af[4], bfr[4];
#pragma unroll
        for (int i = 0; i < 4; ++i)
            af[i] = *(const short8*)&As[(wm * 64 + i * 16 + l16) * BK + quad * 8];
#pragma unroll
        for (int j = 0; j < 4; ++j)
            bfr[j] = *(const short8*)&Bs[(wn * 64 + j * 16 + l16) * BK + quad * 8];
#pragma unroll
        for (int i = 0; i < 4; ++i)
#pragma unroll
            for (int j = 0; j < 4; ++j)
                acc[i][j] = __builtin_amdgcn_mfma_f32_16x16x32_bf16(af[i], bfr[j], acc[i][j], 0, 0, 0);
        __syncthreads();
    }

#pragma unroll
    for (int j = 0; j < 4; ++j) {
        int col = bn + wn * 64 + j * 16 + l16;
        float bv = bias ? bias[col] : 0.f;
#pragma unroll
        for (int i = 0; i < 4; ++i) {
            int row0 = bm + wm * 64 + i * 16 + quad * 4;
#pragma unroll
            for (int rg = 0; rg < 4; ++rg) {
                int row = row0 + rg;
                if (row < M) {
                    float v = acc[i][j][rg] + bv;
                    if constexpr (__is_same(OutT, ushort_t))
                        C[(size_t)row * N + col] = f2bf(v);
                    else
                        C[(size_t)row * N + col] = v;
                }
            }
        }
    }
}

// ---------------- segmented mean-aggregation (no atomics) ----------------
// One block per active (dst, rel) segment. H bf16 [*, dim]. agg fp32 [*, dim].
// blockDim.x == dim/2; thread t owns elements 2t, 2t+1.
__global__ __launch_bounds__(256) void segsum(const ushort_t* __restrict__ H,
                                              float* __restrict__ agg,
                                              const int* __restrict__ off,
                                              const int* __restrict__ cnt,
                                              const int* __restrict__ eid,
                                              const int* __restrict__ src,
                                              const int* __restrict__ act,
                                              const int* __restrict__ nact,
                                              int r, int dim, int n) {
    if ((int)blockIdx.x >= nact[r]) return;
    int d = act[r * n + blockIdx.x];
    int key = d * N_REL + r;
    int c = cnt[key];
    int o = off[key];
    float inv = 1.0f / (float)c;
    int t = threadIdx.x;
    float a0 = 0.f, a1 = 0.f;
    for (int k = o; k < o + c; ++k) {
        int e = eid[k];
        int s = src[e];
        uint_t u = *(const uint_t*)(H + (size_t)s * dim + 2 * t);
        a0 += __uint_as_float(u << 16);
        a1 += __uint_as_float(u & 0xffff0000u);
    }
    float2* p = (float2*)(agg + (size_t)d * dim + 2 * t);
    float2 g = *p;
    g.x += a0 * inv;
    g.y += a1 * inv;
    *p = g;
}

// ---------------- launcher ----------------

extern "C" void kernel_launch(void* const* d_in, const int* in_sizes, int n_in,
                              void* d_out, int out_size, void* d_ws, size_t ws_size,
                              hipStream_t stream) {
    const float* x     = (const float*)d_in[0];
    const int*   eidx  = (const int*)d_in[1];
    const int*   etype = (const int*)d_in[2];
    const float* W1    = (const float*)d_in[3];
    const float* root1 = (const float*)d_in[4];
    const float* b1    = (const float*)d_in[5];
    const float* W2    = (const float*)d_in[6];
    const float* root2 = (const float*)d_in[7];
    const float* b2    = (const float*)d_in[8];
    float* out = (float*)d_out;

    const int IN_DIM = 1280, HID_DIM = 512, OUT_DIM = 256;
    const int E = in_sizes[2];
    const int N = in_sizes[0] / IN_DIM;
    const int NK = N * N_REL;
    const int* srcs = eidx;
    const int* dsts = eidx + E;

    char* ws = (char*)d_ws;
    size_t offb = 0;
    auto alloc = [&](size_t bytes) { void* p = ws + offb; offb += (bytes + 255) & ~(size_t)255; return p; };
    int*      cnt    = (int*)alloc((size_t)NK * 4);
    int*      off    = (int*)alloc((size_t)NK * 4);
    int*      cursor = (int*)alloc((size_t)NK * 4);
    int*      bsum   = (int*)alloc(1024 * 4);
    int*      nact   = (int*)alloc(8 * 4);
    int*      act    = (int*)alloc((size_t)N_REL * N * 4);
    int*      eid    = (int*)alloc((size_t)E * 4);
    ushort_t* x_bf   = (ushort_t*)alloc((size_t)N * IN_DIM * 2);
    ushort_t* W1t    = (ushort_t*)alloc((size_t)N_REL * IN_DIM * HID_DIM * 2);
    ushort_t* r1t    = (ushort_t*)alloc((size_t)IN_DIM * HID_DIM * 2);
    ushort_t* W2t    = (ushort_t*)alloc((size_t)N_REL * HID_DIM * OUT_DIM * 2);
    ushort_t* r2t    = (ushort_t*)alloc((size_t)HID_DIM * OUT_DIM * 2);
    ushort_t* Hr     = (ushort_t*)alloc((size_t)N * HID_DIM * 2);  // per-rel slot (reused L2)
    float*    hbuf   = (float*)alloc((size_t)N * HID_DIM * 4);
    ushort_t* hb_bf  = (ushort_t*)alloc((size_t)N * HID_DIM * 2);
    (void)ws_size;

    const int nb = (NK + 255) / 256;  // 625 scan blocks

    // 1) sort edges by (dst, rel)
    hipMemsetAsync(cnt, 0, (size_t)NK * 4, stream);
    hipMemsetAsync(nact, 0, 8 * 4, stream);
    hist_kernel<<<(E + 255) / 256, 256, 0, stream>>>(dsts, etype, cnt, E);
    scan1<<<nb, 256, 0, stream>>>(cnt, off, bsum, NK);
    scan2<<<1, 1024, 0, stream>>>(bsum, nb);
    scan3<<<nb, 256, 0, stream>>>(cnt, off, bsum, cursor, nact, act, NK, N);
    scatter_ids<<<(E + 255) / 256, 256, 0, stream>>>(dsts, etype, cursor, eid, E);

    // 2) casts / weight transposes
    {
        long n = (long)N * IN_DIM;
        cast_bf16<<<(unsigned)((n / 4 + 255) / 256), 256, 0, stream>>>(x, x_bf, n);
    }
    transpose_cast<<<dim3(HID_DIM / 32, IN_DIM / 32, N_REL), 256, 0, stream>>>(W1, W1t, IN_DIM, HID_DIM);
    transpose_cast<<<dim3(HID_DIM / 32, IN_DIM / 32, 1), 256, 0, stream>>>(root1, r1t, IN_DIM, HID_DIM);
    transpose_cast<<<dim3(OUT_DIM / 32, HID_DIM / 32, N_REL), 256, 0, stream>>>(W2, W2t, HID_DIM, OUT_DIM);
    transpose_cast<<<dim3(OUT_DIM / 32, HID_DIM / 32, 1), 256, 0, stream>>>(root2, r2t, HID_DIM, OUT_DIM);

    const int mblk = (N + TM - 1) / TM;

    // 3) layer 1: hbuf = x@root1 + b1; per-rel GEMM -> bf16 Hr -> segmented mean add
    gemm_bt<float><<<dim3(mblk, HID_DIM / TN), 256, 0, stream>>>(x_bf, r1t, b1, hbuf, N, IN_DIM, HID_DIM);
    for (int r = 0; r < N_REL; ++r) {
        gemm_bt<ushort_t><<<dim3(mblk, HID_DIM / TN), 256, 0, stream>>>(
            x_bf, W1t + (size_t)r * IN_DIM * HID_DIM, nullptr, Hr, N, IN_DIM, HID_DIM);
        segsum<<<N, HID_DIM / 2, 0, stream>>>(Hr, hbuf, off, cnt, eid, srcs, act, nact, r, HID_DIM, N);
    }
    {
        long n = (long)N * HID_DIM;
        relu_cast_bf16<<<(unsigned)((n / 4 + 255) / 256), 256, 0, stream>>>(hbuf, hb_bf, n);
    }

    // 4) layer 2
    gemm_bt<float><<<dim3(mblk, OUT_DIM / TN), 256, 0, stream>>>(hb_bf, r2t, b2, out, N, HID_DIM, OUT_DIM);
    for (int r = 0; r < N_REL; ++r) {
        gemm_bt<ushort_t><<<dim3(mblk, OUT_DIM / TN), 256, 0, stream>>>(
            hb_bf, W2t + (size_t)r * HID_DIM * OUT_DIM, nullptr, Hr, N, HID_DIM, OUT_DIM);
        segsum<<<N, OUT_DIM / 2, 0, stream>>>(Hr, out, off, cnt, eid, srcs, act, nact, r, OUT_DIM, N);
    }
}

// Round 4
// 1377.583 us; speedup vs baseline: 3.8109x; 1.2900x over previous
//
#include <hip/hip_runtime.h>
#include <hip/hip_bf16.h>

#define N_REL 8
#define TM 128
#define TN 128
#define BK 32

typedef unsigned short ushort_t;
typedef unsigned int uint_t;
typedef __attribute__((ext_vector_type(8))) short short8;   // bf16x8 MFMA operand
typedef __attribute__((ext_vector_type(4))) float floatx4;  // MFMA accumulator

static __device__ __forceinline__ ushort_t f2bf(float f) {
    union { float f; unsigned u; } v; v.f = f;
    unsigned r = v.u + 0x7fff + ((v.u >> 16) & 1);
    return (ushort_t)(r >> 16);
}

typedef __attribute__((address_space(1))) void glob_void;
typedef __attribute__((address_space(3))) void lds_void;

static __device__ __forceinline__ void load_lds16(const void* g, void* l) {
    __builtin_amdgcn_global_load_lds((glob_void*)g, (lds_void*)l, 16, 0, 0);
}

// ---------------- sort infrastructure ----------------

__global__ __launch_bounds__(256) void hist_kernel(const int* __restrict__ dst,
                                                   const int* __restrict__ et,
                                                   int* __restrict__ cnt, int E) {
    int e = blockIdx.x * blockDim.x + threadIdx.x;
    if (e < E) atomicAdd(&cnt[dst[e] * N_REL + et[e]], 1);
}

// phase 1: per-256-block exclusive scan, write block sums
__global__ __launch_bounds__(256) void scan1(const int* __restrict__ cnt,
                                             int* __restrict__ off,
                                             int* __restrict__ bsum, int nk) {
    __shared__ int s[256];
    int t = threadIdx.x;
    int k = blockIdx.x * 256 + t;
    int v = k < nk ? cnt[k] : 0;
    s[t] = v; __syncthreads();
    for (int d = 1; d < 256; d <<= 1) {
        int x = (t >= d) ? s[t - d] : 0;
        __syncthreads(); s[t] += x; __syncthreads();
    }
    if (k < nk) off[k] = s[t] - v;          // exclusive
    if (t == 255) bsum[blockIdx.x] = s[255];
}

// phase 2: single block scans block sums (nb <= 1024)
__global__ __launch_bounds__(1024) void scan2(int* __restrict__ bsum, int nb) {
    __shared__ int s[1024];
    int t = threadIdx.x;
    int v = t < nb ? bsum[t] : 0;
    s[t] = v; __syncthreads();
    for (int d = 1; d < 1024; d <<= 1) {
        int x = (t >= d) ? s[t - d] : 0;
        __syncthreads(); s[t] += x; __syncthreads();
    }
    if (t < nb) bsum[t] = s[t] - v;         // exclusive
}

// phase 3: add block offsets, copy to cursor (no atomics)
__global__ __launch_bounds__(256) void scan3(int* __restrict__ off,
                                             const int* __restrict__ bsum,
                                             int* __restrict__ cursor,
                                             int nk) {
    int k = blockIdx.x * 256 + threadIdx.x;
    if (k >= nk) return;
    int o = off[k] + bsum[k >> 8];
    off[k] = o;
    cursor[k] = o;
}

__global__ __launch_bounds__(256) void scatter_ids(const int* __restrict__ dst,
                                                   const int* __restrict__ et,
                                                   int* __restrict__ cursor,
                                                   int* __restrict__ eid, int E) {
    int e = blockIdx.x * blockDim.x + threadIdx.x;
    if (e < E) {
        int key = dst[e] * N_REL + et[e];
        int pos = atomicAdd(&cursor[key], 1);
        eid[pos] = e;
    }
}

// ---------------- casts ----------------

__global__ __launch_bounds__(256) void cast_bf16(const float* __restrict__ in,
                                                 ushort_t* __restrict__ out, long n) {
    long idx = ((long)blockIdx.x * blockDim.x + threadIdx.x) * 4;
    if (idx + 4 <= n) {
        float4 v = *(const float4*)(in + idx);
        ushort_t o[4] = {f2bf(v.x), f2bf(v.y), f2bf(v.z), f2bf(v.w)};
        *(uint2*)(out + idx) = *(const uint2*)o;
    } else {
        for (; idx < n; ++idx) out[idx] = f2bf(in[idx]);
    }
}

__global__ __launch_bounds__(256) void relu_cast_bf16(const float* __restrict__ in,
                                                      ushort_t* __restrict__ out, long n) {
    long idx = ((long)blockIdx.x * blockDim.x + threadIdx.x) * 4;
    if (idx + 4 <= n) {
        float4 v = *(const float4*)(in + idx);
        ushort_t o[4] = {f2bf(fmaxf(v.x, 0.f)), f2bf(fmaxf(v.y, 0.f)),
                         f2bf(fmaxf(v.z, 0.f)), f2bf(fmaxf(v.w, 0.f))};
        *(uint2*)(out + idx) = *(const uint2*)o;
    } else {
        for (; idx < n; ++idx) out[idx] = f2bf(fmaxf(in[idx], 0.f));
    }
}

// in: [z][K][N] fp32 -> out: [z][N][K] bf16.
__global__ __launch_bounds__(256) void transpose_cast(const float* __restrict__ in,
                                                      ushort_t* __restrict__ out,
                                                      int K, int N) {
    __shared__ float tile[32][33];
    const float* inp = in + (size_t)blockIdx.z * K * N;
    ushort_t* outp = out + (size_t)blockIdx.z * K * N;
    int n0 = blockIdx.x * 32, k0 = blockIdx.y * 32;
    int tx = threadIdx.x & 31, ty = threadIdx.x >> 5;
#pragma unroll
    for (int s = 0; s < 4; ++s)
        tile[ty + 8 * s][tx] = inp[(size_t)(k0 + ty + 8 * s) * N + n0 + tx];
    __syncthreads();
#pragma unroll
    for (int s = 0; s < 4; ++s)
        outp[(size_t)(n0 + ty + 8 * s) * K + k0 + tx] = f2bf(tile[tx][ty + 8 * s]);
}

// ---------------- MFMA GEMM: C[M,N] = A[M,K] @ Bt[N,K]^T (+bias) ----------------
template <typename OutT>
__global__ __launch_bounds__(256) void gemm_bt(const ushort_t* __restrict__ A,
                                               const ushort_t* __restrict__ Bt,
                                               const float* __restrict__ bias,
                                               OutT* __restrict__ C,
                                               int M, int K, int N) {
    __shared__ __align__(16) ushort_t As[TM * BK];
    __shared__ __align__(16) ushort_t Bs[TN * BK];

    const int t = threadIdx.x;
    const int lane = t & 63;
    const int wave = t >> 6;
    const int wm = wave >> 1, wn = wave & 1;
    const int quad = lane >> 4, l16 = lane & 15;

    const int bm = blockIdx.x * TM;
    const int bn = blockIdx.y * TN;

    const int ar = lane >> 2;
    const int ac = (lane & 3) * 8;

    floatx4 acc[4][4];
#pragma unroll
    for (int i = 0; i < 4; ++i)
#pragma unroll
        for (int j = 0; j < 4; ++j) acc[i][j] = (floatx4)(0.f);

    for (int k0 = 0; k0 < K; k0 += BK) {
#pragma unroll
        for (int cc = 0; cc < 2; ++cc) {
            const int c = 2 * wave + cc;
            int gra = bm + c * 16 + ar;
            gra = gra < M ? gra : M - 1;
            load_lds16(A + (size_t)gra * K + k0 + ac, As + c * 16 * BK);
            int grb = bn + c * 16 + ar;
            load_lds16(Bt + (size_t)grb * K + k0 + ac, Bs + c * 16 * BK);
        }
        __syncthreads();

        short8 af[4], bfr[4];
#pragma unroll
        for (int i = 0; i < 4; ++i)
            af[i] = *(const short8*)&As[(wm * 64 + i * 16 + l16) * BK + quad * 8];
#pragma unroll
        for (int j = 0; j < 4; ++j)
            bfr[j] = *(const short8*)&Bs[(wn * 64 + j * 16 + l16) * BK + quad * 8];
#pragma unroll
        for (int i = 0; i < 4; ++i)
#pragma unroll
            for (int j = 0; j < 4; ++j)
                acc[i][j] = __builtin_amdgcn_mfma_f32_16x16x32_bf16(af[i], bfr[j], acc[i][j], 0, 0, 0);
        __syncthreads();
    }

#pragma unroll
    for (int j = 0; j < 4; ++j) {
        int col = bn + wn * 64 + j * 16 + l16;
        float bv = bias ? bias[col] : 0.f;
#pragma unroll
        for (int i = 0; i < 4; ++i) {
            int row0 = bm + wm * 64 + i * 16 + quad * 4;
#pragma unroll
            for (int rg = 0; rg < 4; ++rg) {
                int row = row0 + rg;
                if (row < M) {
                    float v = acc[i][j][rg] + bv;
                    if constexpr (__is_same(OutT, ushort_t))
                        C[(size_t)row * N + col] = f2bf(v);
                    else
                        C[(size_t)row * N + col] = v;
                }
            }
        }
    }
}

// ---------------- segmented mean-aggregation (no atomics) ----------------
// One block per dst node; early-exit if segment (dst, rel) empty.
// blockDim.x == dim/2; thread t owns elements 2t, 2t+1.
__global__ __launch_bounds__(256) void segsum(const ushort_t* __restrict__ H,
                                              float* __restrict__ agg,
                                              const int* __restrict__ off,
                                              const int* __restrict__ cnt,
                                              const int* __restrict__ eid,
                                              const int* __restrict__ src,
                                              int r, int dim) {
    int d = blockIdx.x;
    int key = d * N_REL + r;
    int c = cnt[key];
    if (c == 0) return;
    int o = off[key];
    float inv = 1.0f / (float)c;
    int t = threadIdx.x;
    float a0 = 0.f, a1 = 0.f;
    for (int k = o; k < o + c; ++k) {
        int e = eid[k];
        int s = src[e];
        uint_t u = *(const uint_t*)(H + (size_t)s * dim + 2 * t);
        a0 += __uint_as_float(u << 16);
        a1 += __uint_as_float(u & 0xffff0000u);
    }
    float2* p = (float2*)(agg + (size_t)d * dim + 2 * t);
    float2 g = *p;
    g.x += a0 * inv;
    g.y += a1 * inv;
    *p = g;
}

// ---------------- launcher ----------------

extern "C" void kernel_launch(void* const* d_in, const int* in_sizes, int n_in,
                              void* d_out, int out_size, void* d_ws, size_t ws_size,
                              hipStream_t stream) {
    const float* x     = (const float*)d_in[0];
    const int*   eidx  = (const int*)d_in[1];
    const int*   etype = (const int*)d_in[2];
    const float* W1    = (const float*)d_in[3];
    const float* root1 = (const float*)d_in[4];
    const float* b1    = (const float*)d_in[5];
    const float* W2    = (const float*)d_in[6];
    const float* root2 = (const float*)d_in[7];
    const float* b2    = (const float*)d_in[8];
    float* out = (float*)d_out;

    const int IN_DIM = 1280, HID_DIM = 512, OUT_DIM = 256;
    const int E = in_sizes[2];
    const int N = in_sizes[0] / IN_DIM;
    const int NK = N * N_REL;
    const int* srcs = eidx;
    const int* dsts = eidx + E;

    char* ws = (char*)d_ws;
    size_t offb = 0;
    auto alloc = [&](size_t bytes) { void* p = ws + offb; offb += (bytes + 255) & ~(size_t)255; return p; };
    int*      cnt    = (int*)alloc((size_t)NK * 4);
    int*      off    = (int*)alloc((size_t)NK * 4);
    int*      cursor = (int*)alloc((size_t)NK * 4);
    int*      bsum   = (int*)alloc(1024 * 4);
    int*      eid    = (int*)alloc((size_t)E * 4);
    ushort_t* x_bf   = (ushort_t*)alloc((size_t)N * IN_DIM * 2);
    ushort_t* W1t    = (ushort_t*)alloc((size_t)N_REL * IN_DIM * HID_DIM * 2);
    ushort_t* r1t    = (ushort_t*)alloc((size_t)IN_DIM * HID_DIM * 2);
    ushort_t* W2t    = (ushort_t*)alloc((size_t)N_REL * HID_DIM * OUT_DIM * 2);
    ushort_t* r2t    = (ushort_t*)alloc((size_t)HID_DIM * OUT_DIM * 2);
    ushort_t* Hr     = (ushort_t*)alloc((size_t)N * HID_DIM * 2);
    float*    hbuf   = (float*)alloc((size_t)N * HID_DIM * 4);
    ushort_t* hb_bf  = (ushort_t*)alloc((size_t)N * HID_DIM * 2);
    (void)ws_size;

    const int nb = (NK + 255) / 256;

    // 1) sort edges by (dst, rel)
    hipMemsetAsync(cnt, 0, (size_t)NK * 4, stream);
    hist_kernel<<<(E + 255) / 256, 256, 0, stream>>>(dsts, etype, cnt, E);
    scan1<<<nb, 256, 0, stream>>>(cnt, off, bsum, NK);
    scan2<<<1, 1024, 0, stream>>>(bsum, nb);
    scan3<<<nb, 256, 0, stream>>>(off, bsum, cursor, NK);
    scatter_ids<<<(E + 255) / 256, 256, 0, stream>>>(dsts, etype, cursor, eid, E);

    // 2) casts / weight transposes
    {
        long n = (long)N * IN_DIM;
        cast_bf16<<<(unsigned)((n / 4 + 255) / 256), 256, 0, stream>>>(x, x_bf, n);
    }
    transpose_cast<<<dim3(HID_DIM / 32, IN_DIM / 32, N_REL), 256, 0, stream>>>(W1, W1t, IN_DIM, HID_DIM);
    transpose_cast<<<dim3(HID_DIM / 32, IN_DIM / 32, 1), 256, 0, stream>>>(root1, r1t, IN_DIM, HID_DIM);
    transpose_cast<<<dim3(OUT_DIM / 32, HID_DIM / 32, N_REL), 256, 0, stream>>>(W2, W2t, HID_DIM, OUT_DIM);
    transpose_cast<<<dim3(OUT_DIM / 32, HID_DIM / 32, 1), 256, 0, stream>>>(root2, r2t, HID_DIM, OUT_DIM);

    const int mblk = (N + TM - 1) / TM;

    // 3) layer 1
    gemm_bt<float><<<dim3(mblk, HID_DIM / TN), 256, 0, stream>>>(x_bf, r1t, b1, hbuf, N, IN_DIM, HID_DIM);
    for (int r = 0; r < N_REL; ++r) {
        gemm_bt<ushort_t><<<dim3(mblk, HID_DIM / TN), 256, 0, stream>>>(
            x_bf, W1t + (size_t)r * IN_DIM * HID_DIM, nullptr, Hr, N, IN_DIM, HID_DIM);
        segsum<<<N, HID_DIM / 2, 0, stream>>>(Hr, hbuf, off, cnt, eid, srcs, r, HID_DIM);
    }
    {
        long n = (long)N * HID_DIM;
        relu_cast_bf16<<<(unsigned)((n / 4 + 255) / 256), 256, 0, stream>>>(hbuf, hb_bf, n);
    }

    // 4) layer 2
    gemm_bt<float><<<dim3(mblk, OUT_DIM / TN), 256, 0, stream>>>(hb_bf, r2t, b2, out, N, HID_DIM, OUT_DIM);
    for (int r = 0; r < N_REL; ++r) {
        gemm_bt<ushort_t><<<dim3(mblk, OUT_DIM / TN), 256, 0, stream>>>(
            hb_bf, W2t + (size_t)r * HID_DIM * OUT_DIM, nullptr, Hr, N, HID_DIM, OUT_DIM);
        segsum<<<N, OUT_DIM / 2, 0, stream>>>(Hr, out, off, cnt, eid, srcs, r, OUT_DIM);
    }
}

// Round 5
// 1120.913 us; speedup vs baseline: 4.6836x; 1.2290x over previous
//
#include <hip/hip_runtime.h>
#include <hip/hip_bf16.h>

#define N_REL 8
#define TM 128
#define TN 128
#define BK 32

typedef unsigned short ushort_t;
typedef unsigned int uint_t;
typedef __attribute__((ext_vector_type(8))) short short8;   // bf16x8 MFMA operand
typedef __attribute__((ext_vector_type(4))) float floatx4;  // MFMA accumulator

static __device__ __forceinline__ ushort_t f2bf(float f) {
    union { float f; unsigned u; } v; v.f = f;
    unsigned r = v.u + 0x7fff + ((v.u >> 16) & 1);
    return (ushort_t)(r >> 16);
}

typedef __attribute__((address_space(1))) void glob_void;
typedef __attribute__((address_space(3))) void lds_void;

static __device__ __forceinline__ void load_lds16(const void* g, void* l) {
    __builtin_amdgcn_global_load_lds((glob_void*)g, (lds_void*)l, 16, 0, 0);
}

// ---------------- sort infrastructure ----------------

__global__ __launch_bounds__(256) void hist_kernel(const int* __restrict__ dst,
                                                   const int* __restrict__ et,
                                                   int* __restrict__ cnt, int E) {
    int e = blockIdx.x * blockDim.x + threadIdx.x;
    if (e < E) atomicAdd(&cnt[dst[e] * N_REL + et[e]], 1);
}

__global__ __launch_bounds__(256) void scan1(const int* __restrict__ cnt,
                                             int* __restrict__ off,
                                             int* __restrict__ bsum, int nk) {
    __shared__ int s[256];
    int t = threadIdx.x;
    int k = blockIdx.x * 256 + t;
    int v = k < nk ? cnt[k] : 0;
    s[t] = v; __syncthreads();
    for (int d = 1; d < 256; d <<= 1) {
        int x = (t >= d) ? s[t - d] : 0;
        __syncthreads(); s[t] += x; __syncthreads();
    }
    if (k < nk) off[k] = s[t] - v;
    if (t == 255) bsum[blockIdx.x] = s[255];
}

__global__ __launch_bounds__(1024) void scan2(int* __restrict__ bsum, int nb) {
    __shared__ int s[1024];
    int t = threadIdx.x;
    int v = t < nb ? bsum[t] : 0;
    s[t] = v; __syncthreads();
    for (int d = 1; d < 1024; d <<= 1) {
        int x = (t >= d) ? s[t - d] : 0;
        __syncthreads(); s[t] += x; __syncthreads();
    }
    if (t < nb) bsum[t] = s[t] - v;
}

__global__ __launch_bounds__(256) void scan3(int* __restrict__ off,
                                             const int* __restrict__ bsum,
                                             int* __restrict__ cursor,
                                             int nk) {
    int k = blockIdx.x * 256 + threadIdx.x;
    if (k >= nk) return;
    int o = off[k] + bsum[k >> 8];
    off[k] = o;
    cursor[k] = o;
}

__global__ __launch_bounds__(256) void scatter_ids(const int* __restrict__ dst,
                                                   const int* __restrict__ et,
                                                   int* __restrict__ cursor,
                                                   int* __restrict__ eid, int E) {
    int e = blockIdx.x * blockDim.x + threadIdx.x;
    if (e < E) {
        int key = dst[e] * N_REL + et[e];
        int pos = atomicAdd(&cursor[key], 1);
        eid[pos] = e;
    }
}

// ---------------- casts ----------------

__global__ __launch_bounds__(256) void cast_bf16(const float* __restrict__ in,
                                                 ushort_t* __restrict__ out, long n) {
    long idx = ((long)blockIdx.x * blockDim.x + threadIdx.x) * 4;
    if (idx + 4 <= n) {
        float4 v = *(const float4*)(in + idx);
        ushort_t o[4] = {f2bf(v.x), f2bf(v.y), f2bf(v.z), f2bf(v.w)};
        *(uint2*)(out + idx) = *(const uint2*)o;
    } else {
        for (; idx < n; ++idx) out[idx] = f2bf(in[idx]);
    }
}

__global__ __launch_bounds__(256) void relu_cast_bf16(const float* __restrict__ in,
                                                      ushort_t* __restrict__ out, long n) {
    long idx = ((long)blockIdx.x * blockDim.x + threadIdx.x) * 4;
    if (idx + 4 <= n) {
        float4 v = *(const float4*)(in + idx);
        ushort_t o[4] = {f2bf(fmaxf(v.x, 0.f)), f2bf(fmaxf(v.y, 0.f)),
                         f2bf(fmaxf(v.z, 0.f)), f2bf(fmaxf(v.w, 0.f))};
        *(uint2*)(out + idx) = *(const uint2*)o;
    } else {
        for (; idx < n; ++idx) out[idx] = f2bf(fmaxf(in[idx], 0.f));
    }
}

// in: [z][K][N] fp32 -> out: [z][N][K] bf16.
__global__ __launch_bounds__(256) void transpose_cast(const float* __restrict__ in,
                                                      ushort_t* __restrict__ out,
                                                      int K, int N) {
    __shared__ float tile[32][33];
    const float* inp = in + (size_t)blockIdx.z * K * N;
    ushort_t* outp = out + (size_t)blockIdx.z * K * N;
    int n0 = blockIdx.x * 32, k0 = blockIdx.y * 32;
    int tx = threadIdx.x & 31, ty = threadIdx.x >> 5;
#pragma unroll
    for (int s = 0; s < 4; ++s)
        tile[ty + 8 * s][tx] = inp[(size_t)(k0 + ty + 8 * s) * N + n0 + tx];
    __syncthreads();
#pragma unroll
    for (int s = 0; s < 4; ++s)
        outp[(size_t)(n0 + ty + 8 * s) * K + k0 + tx] = f2bf(tile[tx][ty + 8 * s]);
}

// ---------------- MFMA GEMM: C[M,N] = A[M,K] @ Bt[N,K]^T (+bias) ----------------
// grid = (N/TN, ceil(M/TM)); bn varies fastest so the whole B batch stays L2-resident
// while x streams once.
template <typename OutT>
__global__ __launch_bounds__(256) void gemm_bt(const ushort_t* __restrict__ A,
                                               const ushort_t* __restrict__ Bt,
                                               const float* __restrict__ bias,
                                               OutT* __restrict__ C,
                                               int M, int K, int N) {
    __shared__ __align__(16) ushort_t As[TM * BK];
    __shared__ __align__(16) ushort_t Bs[TN * BK];

    const int t = threadIdx.x;
    const int lane = t & 63;
    const int wave = t >> 6;
    const int wm = wave >> 1, wn = wave & 1;
    const int quad = lane >> 4, l16 = lane & 15;

    const int bm = blockIdx.y * TM;
    const int bn = blockIdx.x * TN;

    const int ar = lane >> 2;
    const int ac = (lane & 3) * 8;

    floatx4 acc[4][4];
#pragma unroll
    for (int i = 0; i < 4; ++i)
#pragma unroll
        for (int j = 0; j < 4; ++j) acc[i][j] = (floatx4)(0.f);

    for (int k0 = 0; k0 < K; k0 += BK) {
#pragma unroll
        for (int cc = 0; cc < 2; ++cc) {
            const int c = 2 * wave + cc;
            int gra = bm + c * 16 + ar;
            gra = gra < M ? gra : M - 1;
            load_lds16(A + (size_t)gra * K + k0 + ac, As + c * 16 * BK);
            int grb = bn + c * 16 + ar;
            load_lds16(Bt + (size_t)grb * K + k0 + ac, Bs + c * 16 * BK);
        }
        __syncthreads();

        short8 af[4], bfr[4];
#pragma unroll
        for (int i = 0; i < 4; ++i)
            af[i] = *(const short8*)&As[(wm * 64 + i * 16 + l16) * BK + quad * 8];
#pragma unroll
        for (int j = 0; j < 4; ++j)
            bfr[j] = *(const short8*)&Bs[(wn * 64 + j * 16 + l16) * BK + quad * 8];
#pragma unroll
        for (int i = 0; i < 4; ++i)
#pragma unroll
            for (int j = 0; j < 4; ++j)
                acc[i][j] = __builtin_amdgcn_mfma_f32_16x16x32_bf16(af[i], bfr[j], acc[i][j], 0, 0, 0);
        __syncthreads();
    }

#pragma unroll
    for (int j = 0; j < 4; ++j) {
        int col = bn + wn * 64 + j * 16 + l16;
        float bv = bias ? bias[col] : 0.f;
#pragma unroll
        for (int i = 0; i < 4; ++i) {
            int row0 = bm + wm * 64 + i * 16 + quad * 4;
#pragma unroll
            for (int rg = 0; rg < 4; ++rg) {
                int row = row0 + rg;
                if (row < M) {
                    float v = acc[i][j][rg] + bv;
                    if constexpr (__is_same(OutT, ushort_t))
                        C[(size_t)row * N + col] = f2bf(v);
                    else
                        C[(size_t)row * N + col] = v;
                }
            }
        }
    }
}

// ---------------- fused multi-relation segmented mean (no atomics) ----------------
// One block per dst. H bf16 [*, hstride], relation rr occupies cols [rr*dim, (rr+1)*dim).
// blockDim.x == dim/2; thread t owns elements 2t, 2t+1. agg row touched once.
__global__ __launch_bounds__(256) void segsum_multi(const ushort_t* __restrict__ H,
                                                    float* __restrict__ agg,
                                                    const int* __restrict__ off,
                                                    const int* __restrict__ cnt,
                                                    const int* __restrict__ eid,
                                                    const int* __restrict__ src,
                                                    int rbase, int rcount,
                                                    int dim, int hstride) {
    int d = blockIdx.x;
    int t = threadIdx.x;
    float a0 = 0.f, a1 = 0.f;
    bool any = false;
    for (int rr = 0; rr < rcount; ++rr) {
        int key = d * N_REL + rbase + rr;
        int c = cnt[key];
        if (c == 0) continue;
        any = true;
        int o = off[key];
        float s0 = 0.f, s1 = 0.f;
        const ushort_t* Hr = H + rr * dim + 2 * t;
        for (int k = o; k < o + c; ++k) {
            int e = eid[k];
            int s = src[e];
            uint_t u = *(const uint_t*)(Hr + (size_t)s * hstride);
            s0 += __uint_as_float(u << 16);
            s1 += __uint_as_float(u & 0xffff0000u);
        }
        float inv = 1.0f / (float)c;
        a0 += s0 * inv;
        a1 += s1 * inv;
    }
    if (!any) return;
    float2* p = (float2*)(agg + (size_t)d * dim + 2 * t);
    float2 g = *p;
    g.x += a0;
    g.y += a1;
    *p = g;
}

// ---------------- launcher ----------------

extern "C" void kernel_launch(void* const* d_in, const int* in_sizes, int n_in,
                              void* d_out, int out_size, void* d_ws, size_t ws_size,
                              hipStream_t stream) {
    const float* x     = (const float*)d_in[0];
    const int*   eidx  = (const int*)d_in[1];
    const int*   etype = (const int*)d_in[2];
    const float* W1    = (const float*)d_in[3];
    const float* root1 = (const float*)d_in[4];
    const float* b1    = (const float*)d_in[5];
    const float* W2    = (const float*)d_in[6];
    const float* root2 = (const float*)d_in[7];
    const float* b2    = (const float*)d_in[8];
    float* out = (float*)d_out;

    const int IN_DIM = 1280, HID_DIM = 512, OUT_DIM = 256;
    const int E = in_sizes[2];
    const int N = in_sizes[0] / IN_DIM;
    const int NK = N * N_REL;
    const int* srcs = eidx;
    const int* dsts = eidx + E;

    char* ws = (char*)d_ws;
    size_t offb = 0;
    auto alloc = [&](size_t bytes) { void* p = ws + offb; offb += (bytes + 255) & ~(size_t)255; return p; };
    int*      cnt    = (int*)alloc((size_t)NK * 4);
    int*      off    = (int*)alloc((size_t)NK * 4);
    int*      cursor = (int*)alloc((size_t)NK * 4);
    int*      bsum   = (int*)alloc(1024 * 4);
    int*      eid    = (int*)alloc((size_t)E * 4);
    ushort_t* x_bf   = (ushort_t*)alloc((size_t)N * IN_DIM * 2);   // later reused for hb_bf
    ushort_t* W1t    = (ushort_t*)alloc((size_t)N_REL * IN_DIM * HID_DIM * 2);
    ushort_t* r1t    = (ushort_t*)alloc((size_t)IN_DIM * HID_DIM * 2);
    ushort_t* W2t    = (ushort_t*)alloc((size_t)N_REL * HID_DIM * OUT_DIM * 2);
    ushort_t* r2t    = (ushort_t*)alloc((size_t)HID_DIM * OUT_DIM * 2);
    ushort_t* Hb     = (ushort_t*)alloc((size_t)N * 1024 * 2);     // batched H (2 rels L1 / 4 rels L2)
    float*    hbuf   = (float*)alloc((size_t)N * HID_DIM * 4);
    ushort_t* hb_bf  = x_bf;  // x_bf dead after layer-1 GEMMs
    (void)ws_size;

    const int nb = (NK + 255) / 256;

    // 1) sort edges by (dst, rel)
    hipMemsetAsync(cnt, 0, (size_t)NK * 4, stream);
    hist_kernel<<<(E + 255) / 256, 256, 0, stream>>>(dsts, etype, cnt, E);
    scan1<<<nb, 256, 0, stream>>>(cnt, off, bsum, NK);
    scan2<<<1, 1024, 0, stream>>>(bsum, nb);
    scan3<<<nb, 256, 0, stream>>>(off, bsum, cursor, NK);
    scatter_ids<<<(E + 255) / 256, 256, 0, stream>>>(dsts, etype, cursor, eid, E);

    // 2) casts / weight transposes
    {
        long n = (long)N * IN_DIM;
        cast_bf16<<<(unsigned)((n / 4 + 255) / 256), 256, 0, stream>>>(x, x_bf, n);
    }
    transpose_cast<<<dim3(HID_DIM / 32, IN_DIM / 32, N_REL), 256, 0, stream>>>(W1, W1t, IN_DIM, HID_DIM);
    transpose_cast<<<dim3(HID_DIM / 32, IN_DIM / 32, 1), 256, 0, stream>>>(root1, r1t, IN_DIM, HID_DIM);
    transpose_cast<<<dim3(OUT_DIM / 32, HID_DIM / 32, N_REL), 256, 0, stream>>>(W2, W2t, HID_DIM, OUT_DIM);
    transpose_cast<<<dim3(OUT_DIM / 32, HID_DIM / 32, 1), 256, 0, stream>>>(root2, r2t, HID_DIM, OUT_DIM);

    const int mblk = (N + TM - 1) / TM;

    // 3) layer 1: root GEMM into fp32 hbuf, then 4 batches of 2 relations
    gemm_bt<float><<<dim3(HID_DIM / TN, mblk), 256, 0, stream>>>(x_bf, r1t, b1, hbuf, N, IN_DIM, HID_DIM);
    for (int b = 0; b < 4; ++b) {
        const int RB = 2, NB = RB * HID_DIM;  // 1024
        gemm_bt<ushort_t><<<dim3(NB / TN, mblk), 256, 0, stream>>>(
            x_bf, W1t + (size_t)b * RB * HID_DIM * IN_DIM, nullptr, Hb, N, IN_DIM, NB);
        segsum_multi<<<N, HID_DIM / 2, 0, stream>>>(Hb, hbuf, off, cnt, eid, srcs,
                                                    b * RB, RB, HID_DIM, NB);
    }
    {
        long n = (long)N * HID_DIM;
        relu_cast_bf16<<<(unsigned)((n / 4 + 255) / 256), 256, 0, stream>>>(hbuf, hb_bf, n);
    }

    // 4) layer 2: root GEMM into out, then 2 batches of 4 relations
    gemm_bt<float><<<dim3(OUT_DIM / TN, mblk), 256, 0, stream>>>(hb_bf, r2t, b2, out, N, HID_DIM, OUT_DIM);
    for (int b = 0; b < 2; ++b) {
        const int RB = 4, NB = RB * OUT_DIM;  // 1024
        gemm_bt<ushort_t><<<dim3(NB / TN, mblk), 256, 0, stream>>>(
            hb_bf, W2t + (size_t)b * RB * OUT_DIM * HID_DIM, nullptr, Hb, N, HID_DIM, NB);
        segsum_multi<<<N, OUT_DIM / 2, 0, stream>>>(Hb, out, off, cnt, eid, srcs,
                                                    b * RB, RB, OUT_DIM, NB);
    }
}

// Round 6
// 949.764 us; speedup vs baseline: 5.5276x; 1.1802x over previous
//
#include <hip/hip_runtime.h>
#include <hip/hip_bf16.h>

#define N_REL 8
#define TM 128
#define TN 128
#define BK 32

typedef unsigned short ushort_t;
typedef unsigned int uint_t;
typedef __attribute__((ext_vector_type(8))) short short8;   // bf16x8 MFMA operand
typedef __attribute__((ext_vector_type(4))) float floatx4;  // MFMA accumulator

static __device__ __forceinline__ ushort_t f2bf(float f) {
    union { float f; unsigned u; } v; v.f = f;
    unsigned r = v.u + 0x7fff + ((v.u >> 16) & 1);
    return (ushort_t)(r >> 16);
}

typedef __attribute__((address_space(1))) void glob_void;
typedef __attribute__((address_space(3))) void lds_void;

static __device__ __forceinline__ void load_lds16(const void* g, void* l) {
    __builtin_amdgcn_global_load_lds((glob_void*)g, (lds_void*)l, 16, 0, 0);
}

// ---------------- sort infrastructure ----------------

__global__ __launch_bounds__(256) void hist_kernel(const int* __restrict__ dst,
                                                   const int* __restrict__ et,
                                                   int* __restrict__ cnt, int E) {
    int e = blockIdx.x * blockDim.x + threadIdx.x;
    if (e < E) atomicAdd(&cnt[dst[e] * N_REL + et[e]], 1);
}

__global__ __launch_bounds__(256) void scan1(const int* __restrict__ cnt,
                                             int* __restrict__ off,
                                             int* __restrict__ bsum, int nk) {
    __shared__ int s[256];
    int t = threadIdx.x;
    int k = blockIdx.x * 256 + t;
    int v = k < nk ? cnt[k] : 0;
    s[t] = v; __syncthreads();
    for (int d = 1; d < 256; d <<= 1) {
        int x = (t >= d) ? s[t - d] : 0;
        __syncthreads(); s[t] += x; __syncthreads();
    }
    if (k < nk) off[k] = s[t] - v;
    if (t == 255) bsum[blockIdx.x] = s[255];
}

__global__ __launch_bounds__(1024) void scan2(int* __restrict__ bsum, int nb) {
    __shared__ int s[1024];
    int t = threadIdx.x;
    int v = t < nb ? bsum[t] : 0;
    s[t] = v; __syncthreads();
    for (int d = 1; d < 1024; d <<= 1) {
        int x = (t >= d) ? s[t - d] : 0;
        __syncthreads(); s[t] += x; __syncthreads();
    }
    if (t < nb) bsum[t] = s[t] - v;
}

__global__ __launch_bounds__(256) void scan3(int* __restrict__ off,
                                             const int* __restrict__ bsum,
                                             int* __restrict__ cursor,
                                             int nk) {
    int k = blockIdx.x * 256 + threadIdx.x;
    if (k >= nk) return;
    int o = off[k] + bsum[k >> 8];
    off[k] = o;
    cursor[k] = o;
}

__global__ __launch_bounds__(256) void scatter_ids(const int* __restrict__ dst,
                                                   const int* __restrict__ et,
                                                   int* __restrict__ cursor,
                                                   int* __restrict__ eid, int E) {
    int e = blockIdx.x * blockDim.x + threadIdx.x;
    if (e < E) {
        int key = dst[e] * N_REL + et[e];
        int pos = atomicAdd(&cursor[key], 1);
        eid[pos] = e;
    }
}

// ---------------- casts ----------------

__global__ __launch_bounds__(256) void cast_bf16(const float* __restrict__ in,
                                                 ushort_t* __restrict__ out, long n) {
    long idx = ((long)blockIdx.x * blockDim.x + threadIdx.x) * 4;
    if (idx + 4 <= n) {
        float4 v = *(const float4*)(in + idx);
        ushort_t o[4] = {f2bf(v.x), f2bf(v.y), f2bf(v.z), f2bf(v.w)};
        *(uint2*)(out + idx) = *(const uint2*)o;
    } else {
        for (; idx < n; ++idx) out[idx] = f2bf(in[idx]);
    }
}

__global__ __launch_bounds__(256) void relu_cast_bf16(const float* __restrict__ in,
                                                      ushort_t* __restrict__ out, long n) {
    long idx = ((long)blockIdx.x * blockDim.x + threadIdx.x) * 4;
    if (idx + 4 <= n) {
        float4 v = *(const float4*)(in + idx);
        ushort_t o[4] = {f2bf(fmaxf(v.x, 0.f)), f2bf(fmaxf(v.y, 0.f)),
                         f2bf(fmaxf(v.z, 0.f)), f2bf(fmaxf(v.w, 0.f))};
        *(uint2*)(out + idx) = *(const uint2*)o;
    } else {
        for (; idx < n; ++idx) out[idx] = f2bf(fmaxf(in[idx], 0.f));
    }
}

// in: [z][K][N] fp32 -> out: [z][N][K] bf16.
__global__ __launch_bounds__(256) void transpose_cast(const float* __restrict__ in,
                                                      ushort_t* __restrict__ out,
                                                      int K, int N) {
    __shared__ float tile[32][33];
    const float* inp = in + (size_t)blockIdx.z * K * N;
    ushort_t* outp = out + (size_t)blockIdx.z * K * N;
    int n0 = blockIdx.x * 32, k0 = blockIdx.y * 32;
    int tx = threadIdx.x & 31, ty = threadIdx.x >> 5;
#pragma unroll
    for (int s = 0; s < 4; ++s)
        tile[ty + 8 * s][tx] = inp[(size_t)(k0 + ty + 8 * s) * N + n0 + tx];
    __syncthreads();
#pragma unroll
    for (int s = 0; s < 4; ++s)
        outp[(size_t)(n0 + ty + 8 * s) * K + k0 + tx] = f2bf(tile[tx][ty + 8 * s]);
}

// ---------------- MFMA GEMM: C[M,N] = A[M,K] @ Bt[N,K]^T (+bias) ----------------
// XCD-aware swizzle: dispatch is round-robin over 8 XCDs (block linear % 8), so we
// remap linear -> (linear%8)*(total/8) + linear/8. Each XCD then owns a contiguous
// bm-chunk (all bn), so A is fetched once per XCD instead of once per bn-block.
// Launcher guarantees gridDim.x*gridDim.y % 8 == 0 (ny padded; OOB bm returns).
template <typename OutT>
__global__ __launch_bounds__(256) void gemm_bt(const ushort_t* __restrict__ A,
                                               const ushort_t* __restrict__ Bt,
                                               const float* __restrict__ bias,
                                               OutT* __restrict__ C,
                                               int M, int K, int N) {
    __shared__ union {
        struct { __align__(16) ushort_t A[TM * BK]; __align__(16) ushort_t B[TN * BK]; } st;
        __align__(16) ushort_t c[32 * TN];   // bf16 epilogue staging (8 KB), aliased
    } sh;

    const int t = threadIdx.x;
    const int lane = t & 63;
    const int wave = t >> 6;
    const int wm = wave >> 1, wn = wave & 1;
    const int quad = lane >> 4, l16 = lane & 15;

    const int nx = gridDim.x;
    const int total = nx * gridDim.y;
    int linear = blockIdx.y * nx + blockIdx.x;
    const int nper = total >> 3;
    linear = (linear & 7) * nper + (linear >> 3);
    const int bm = (linear / nx) * TM;
    const int bn = (linear % nx) * TN;
    if (bm >= M) return;

    const int ar = lane >> 2;
    const int ac = (lane & 3) * 8;

    floatx4 acc[4][4];
#pragma unroll
    for (int i = 0; i < 4; ++i)
#pragma unroll
        for (int j = 0; j < 4; ++j) acc[i][j] = (floatx4)(0.f);

    for (int k0 = 0; k0 < K; k0 += BK) {
#pragma unroll
        for (int cc = 0; cc < 2; ++cc) {
            const int c = 2 * wave + cc;
            int gra = bm + c * 16 + ar;
            gra = gra < M ? gra : M - 1;
            load_lds16(A + (size_t)gra * K + k0 + ac, sh.st.A + c * 16 * BK);
            int grb = bn + c * 16 + ar;
            load_lds16(Bt + (size_t)grb * K + k0 + ac, sh.st.B + c * 16 * BK);
        }
        __syncthreads();

        short8 af[4], bfr[4];
#pragma unroll
        for (int i = 0; i < 4; ++i)
            af[i] = *(const short8*)&sh.st.A[(wm * 64 + i * 16 + l16) * BK + quad * 8];
#pragma unroll
        for (int j = 0; j < 4; ++j)
            bfr[j] = *(const short8*)&sh.st.B[(wn * 64 + j * 16 + l16) * BK + quad * 8];
#pragma unroll
        for (int i = 0; i < 4; ++i)
#pragma unroll
            for (int j = 0; j < 4; ++j)
                acc[i][j] = __builtin_amdgcn_mfma_f32_16x16x32_bf16(af[i], bfr[j], acc[i][j], 0, 0, 0);
        __syncthreads();
    }

    if constexpr (__is_same(OutT, ushort_t)) {
        // LDS-staged epilogue: 4 passes x 32 rows, full-line 16B/lane stores.
#pragma unroll
        for (int i = 0; i < 4; ++i) {
#pragma unroll
            for (int j = 0; j < 4; ++j) {
                int col = wn * 64 + j * 16 + l16;
                float bv = bias ? bias[bn + col] : 0.f;
#pragma unroll
                for (int rg = 0; rg < 4; ++rg)
                    sh.c[(wm * 16 + quad * 4 + rg) * TN + col] = f2bf(acc[i][j][rg] + bv);
            }
            __syncthreads();
#pragma unroll
            for (int s = 0; s < 2; ++s) {
                int lr = s * 16 + (t >> 4);          // 0..31
                int c8 = (t & 15) * 8;               // col (bf16 units), 16 B chunks
                int grow = bm + (lr >> 4) * 64 + i * 16 + (lr & 15);
                if (grow < M)
                    *(uint4*)(C + (size_t)grow * N + bn + c8) = *(const uint4*)&sh.c[lr * TN + c8];
            }
            __syncthreads();
        }
    } else {
#pragma unroll
        for (int j = 0; j < 4; ++j) {
            int col = bn + wn * 64 + j * 16 + l16;
            float bv = bias ? bias[col] : 0.f;
#pragma unroll
            for (int i = 0; i < 4; ++i) {
                int row0 = bm + wm * 64 + i * 16 + quad * 4;
#pragma unroll
                for (int rg = 0; rg < 4; ++rg) {
                    int row = row0 + rg;
                    if (row < M) C[(size_t)row * N + col] = acc[i][j][rg] + bv;
                }
            }
        }
    }
}

// ---------------- fused multi-relation segmented mean (no atomics) ----------------
__global__ __launch_bounds__(256) void segsum_multi(const ushort_t* __restrict__ H,
                                                    float* __restrict__ agg,
                                                    const int* __restrict__ off,
                                                    const int* __restrict__ cnt,
                                                    const int* __restrict__ eid,
                                                    const int* __restrict__ src,
                                                    int rbase, int rcount,
                                                    int dim, int hstride) {
    int d = blockIdx.x;
    int t = threadIdx.x;
    float a0 = 0.f, a1 = 0.f;
    bool any = false;
    for (int rr = 0; rr < rcount; ++rr) {
        int key = d * N_REL + rbase + rr;
        int c = cnt[key];
        if (c == 0) continue;
        any = true;
        int o = off[key];
        float s0 = 0.f, s1 = 0.f;
        const ushort_t* Hr = H + rr * dim + 2 * t;
        for (int k = o; k < o + c; ++k) {
            int e = eid[k];
            int s = src[e];
            uint_t u = *(const uint_t*)(Hr + (size_t)s * hstride);
            s0 += __uint_as_float(u << 16);
            s1 += __uint_as_float(u & 0xffff0000u);
        }
        float inv = 1.0f / (float)c;
        a0 += s0 * inv;
        a1 += s1 * inv;
    }
    if (!any) return;
    float2* p = (float2*)(agg + (size_t)d * dim + 2 * t);
    float2 g = *p;
    g.x += a0;
    g.y += a1;
    *p = g;
}

// ---------------- launcher ----------------

extern "C" void kernel_launch(void* const* d_in, const int* in_sizes, int n_in,
                              void* d_out, int out_size, void* d_ws, size_t ws_size,
                              hipStream_t stream) {
    const float* x     = (const float*)d_in[0];
    const int*   eidx  = (const int*)d_in[1];
    const int*   etype = (const int*)d_in[2];
    const float* W1    = (const float*)d_in[3];
    const float* root1 = (const float*)d_in[4];
    const float* b1    = (const float*)d_in[5];
    const float* W2    = (const float*)d_in[6];
    const float* root2 = (const float*)d_in[7];
    const float* b2    = (const float*)d_in[8];
    float* out = (float*)d_out;

    const int IN_DIM = 1280, HID_DIM = 512, OUT_DIM = 256;
    const int E = in_sizes[2];
    const int N = in_sizes[0] / IN_DIM;
    const int NK = N * N_REL;
    const int* srcs = eidx;
    const int* dsts = eidx + E;

    char* ws = (char*)d_ws;
    size_t offb = 0;
    auto alloc = [&](size_t bytes) { void* p = ws + offb; offb += (bytes + 255) & ~(size_t)255; return p; };
    int*      cnt    = (int*)alloc((size_t)NK * 4);
    int*      off    = (int*)alloc((size_t)NK * 4);
    int*      cursor = (int*)alloc((size_t)NK * 4);
    int*      bsum   = (int*)alloc(1024 * 4);
    int*      eid    = (int*)alloc((size_t)E * 4);
    ushort_t* x_bf   = (ushort_t*)alloc((size_t)N * IN_DIM * 2);   // later reused for hb_bf
    ushort_t* W1t    = (ushort_t*)alloc((size_t)N_REL * IN_DIM * HID_DIM * 2);
    ushort_t* r1t    = (ushort_t*)alloc((size_t)IN_DIM * HID_DIM * 2);
    ushort_t* W2t    = (ushort_t*)alloc((size_t)N_REL * HID_DIM * OUT_DIM * 2);
    ushort_t* r2t    = (ushort_t*)alloc((size_t)HID_DIM * OUT_DIM * 2);
    ushort_t* Hb     = (ushort_t*)alloc((size_t)N * 1024 * 2);
    float*    hbuf   = (float*)alloc((size_t)N * HID_DIM * 4);
    ushort_t* hb_bf  = x_bf;  // x_bf dead after layer-1 GEMMs
    (void)ws_size;

    const int nb = (NK + 255) / 256;

    // 1) sort edges by (dst, rel)
    hipMemsetAsync(cnt, 0, (size_t)NK * 4, stream);
    hist_kernel<<<(E + 255) / 256, 256, 0, stream>>>(dsts, etype, cnt, E);
    scan1<<<nb, 256, 0, stream>>>(cnt, off, bsum, NK);
    scan2<<<1, 1024, 0, stream>>>(bsum, nb);
    scan3<<<nb, 256, 0, stream>>>(off, bsum, cursor, NK);
    scatter_ids<<<(E + 255) / 256, 256, 0, stream>>>(dsts, etype, cursor, eid, E);

    // 2) casts / weight transposes
    {
        long n = (long)N * IN_DIM;
        cast_bf16<<<(unsigned)((n / 4 + 255) / 256), 256, 0, stream>>>(x, x_bf, n);
    }
    transpose_cast<<<dim3(HID_DIM / 32, IN_DIM / 32, N_REL), 256, 0, stream>>>(W1, W1t, IN_DIM, HID_DIM);
    transpose_cast<<<dim3(HID_DIM / 32, IN_DIM / 32, 1), 256, 0, stream>>>(root1, r1t, IN_DIM, HID_DIM);
    transpose_cast<<<dim3(OUT_DIM / 32, HID_DIM / 32, N_REL), 256, 0, stream>>>(W2, W2t, HID_DIM, OUT_DIM);
    transpose_cast<<<dim3(OUT_DIM / 32, HID_DIM / 32, 1), 256, 0, stream>>>(root2, r2t, HID_DIM, OUT_DIM);

    const int mblk = (N + TM - 1) / TM;
    const int mpad = ((mblk + 7) / 8) * 8;  // grid total % 8 == 0 for any nx -> bijective swizzle

    // 3) layer 1: root GEMM into fp32 hbuf, then 4 batches of 2 relations
    gemm_bt<float><<<dim3(HID_DIM / TN, mpad), 256, 0, stream>>>(x_bf, r1t, b1, hbuf, N, IN_DIM, HID_DIM);
    for (int b = 0; b < 4; ++b) {
        const int RB = 2, NB = RB * HID_DIM;  // 1024
        gemm_bt<ushort_t><<<dim3(NB / TN, mpad), 256, 0, stream>>>(
            x_bf, W1t + (size_t)b * RB * HID_DIM * IN_DIM, nullptr, Hb, N, IN_DIM, NB);
        segsum_multi<<<N, HID_DIM / 2, 0, stream>>>(Hb, hbuf, off, cnt, eid, srcs,
                                                    b * RB, RB, HID_DIM, NB);
    }
    {
        long n = (long)N * HID_DIM;
        relu_cast_bf16<<<(unsigned)((n / 4 + 255) / 256), 256, 0, stream>>>(hbuf, hb_bf, n);
    }

    // 4) layer 2: root GEMM into out, then 2 batches of 4 relations
    gemm_bt<float><<<dim3(OUT_DIM / TN, mpad), 256, 0, stream>>>(hb_bf, r2t, b2, out, N, HID_DIM, OUT_DIM);
    for (int b = 0; b < 2; ++b) {
        const int RB = 4, NB = RB * OUT_DIM;  // 1024
        gemm_bt<ushort_t><<<dim3(NB / TN, mpad), 256, 0, stream>>>(
            hb_bf, W2t + (size_t)b * RB * OUT_DIM * HID_DIM, nullptr, Hb, N, HID_DIM, NB);
        segsum_multi<<<N, OUT_DIM / 2, 0, stream>>>(Hb, out, off, cnt, eid, srcs,
                                                    b * RB, RB, OUT_DIM, NB);
    }
}